// Round 1
// baseline (867.072 us; speedup 1.0000x reference)
//
#include <hip/hip_runtime.h>

#define BLOCK 256
#define ROWS 4   // rows per thread; weight SGPR loads amortized 4x, 4-way FMA ILP

struct WPtrs {
    const float* w[19];
    const float* b[19];
};

enum LId {FU1,FU2,KU1,KU2,HU1,HU2,MD1,MD2,MD3,HD1,HD2,KD1,KD2,HA1,HA2,KA1,KA2,FA1,FA2};

// Dense layer over ROWS independent rows. Row loop is INNERMOST so each
// wave-uniform weight value (SGPR via s_load) feeds ROWS independent
// v_fmac_f32 back-to-back: hides scalar-cache latency and fmac chain latency.
template<int DIN,int DOUT,bool RELU>
__device__ __forceinline__ void lin4(const float (&in)[ROWS][DIN], float (&out)[ROWS][DOUT],
                                     const float* __restrict__ w, const float* __restrict__ b) {
#pragma unroll
    for (int j = 0; j < DOUT; ++j) {
        const float bj = b[j];
        float acc[ROWS];
#pragma unroll
        for (int k = 0; k < ROWS; ++k) acc[k] = bj;
#pragma unroll
        for (int i = 0; i < DIN; ++i) {
            const float wv = w[i*DOUT + j];
#pragma unroll
            for (int k = 0; k < ROWS; ++k)
                acc[k] = __builtin_fmaf(in[k][i], wv, acc[k]);
        }
#pragma unroll
        for (int k = 0; k < ROWS; ++k)
            out[k][j] = RELU ? fmaxf(acc[k], 0.0f) : acc[k];
    }
}

__global__ __launch_bounds__(BLOCK) void pnet_kernel(
    const float* __restrict__ x, float* __restrict__ out, int B, WPtrs P) {
    const int tid  = threadIdx.x;
    const int base = blockIdx.x * (BLOCK * ROWS) + tid;

    // ---- load 11 features for each of ROWS rows ----
    // rows at stride BLOCK keep each sub-row's wave access coalesced.
    int row[ROWS];
    float xin[ROWS][11];
#pragma unroll
    for (int k = 0; k < ROWS; ++k) {
        row[k] = base + k * BLOCK;
        const int r = row[k] < B ? row[k] : (B - 1);   // clamp: safe load, store guarded below
        const float* pr = x + (long long)r * 11;
#pragma unroll
        for (int c = 0; c < 11; ++c) xin[k][c] = pr[c];
    }

    // ---- f_up: [f, fd] -> 2 -> 2 ----
    float fin[ROWS][2], tf[ROWS][2], f_up[ROWS][2];
#pragma unroll
    for (int k = 0; k < ROWS; ++k) { fin[k][0] = xin[k][4]; fin[k][1] = xin[k][10]; }
    lin4<2,2,true>(fin, tf, P.w[FU1], P.b[FU1]);
    lin4<2,2,true>(tf, f_up, P.w[FU2], P.b[FU2]);

    // ---- k_up: [k, kd, f_up] -> 4 -> 4 ----
    float kin[ROWS][4], tk[ROWS][4], k_up[ROWS][4];
#pragma unroll
    for (int k = 0; k < ROWS; ++k) {
        kin[k][0] = xin[k][3]; kin[k][1] = xin[k][9];
        kin[k][2] = f_up[k][0]; kin[k][3] = f_up[k][1];
    }
    lin4<4,4,true>(kin, tk, P.w[KU1], P.b[KU1]);
    lin4<4,4,true>(tk, k_up, P.w[KU2], P.b[KU2]);

    // ---- h_up: [h, hd, k_up] -> 6 -> 6 ----
    float hin[ROWS][6], th[ROWS][6], h_up[ROWS][6];
#pragma unroll
    for (int k = 0; k < ROWS; ++k) {
        hin[k][0] = xin[k][2]; hin[k][1] = xin[k][8];
        hin[k][2] = k_up[k][0]; hin[k][3] = k_up[k][1];
        hin[k][4] = k_up[k][2]; hin[k][5] = k_up[k][3];
    }
    lin4<6,6,true>(hin, th, P.w[HU1], P.b[HU1]);
    lin4<6,6,true>(th, h_up, P.w[HU2], P.b[HU2]);

    // ---- m_down: [m_obs(5), h_up(6)] -> 16 -> 16 -> 6 ----
    float min_[ROWS][11], t16a[ROWS][16], t16b[ROWS][16], m_down[ROWS][6];
#pragma unroll
    for (int k = 0; k < ROWS; ++k) {
        min_[k][0] = xin[k][0]; min_[k][1] = xin[k][1]; min_[k][2] = xin[k][5];
        min_[k][3] = xin[k][6]; min_[k][4] = xin[k][7];
        min_[k][5] = h_up[k][0]; min_[k][6] = h_up[k][1]; min_[k][7] = h_up[k][2];
        min_[k][8] = h_up[k][3]; min_[k][9] = h_up[k][4]; min_[k][10] = h_up[k][5];
    }
    lin4<11,16,true>(min_, t16a, P.w[MD1], P.b[MD1]);
    lin4<16,16,true>(t16a, t16b, P.w[MD2], P.b[MD2]);
    lin4<16,6,true>(t16b, m_down, P.w[MD3], P.b[MD3]);

    // ---- h_down: m_down -> 4 -> 4 ----
    float t4b[ROWS][4], h_down[ROWS][4];
    lin4<6,4,true>(m_down, t4b, P.w[HD1], P.b[HD1]);
    lin4<4,4,true>(t4b, h_down, P.w[HD2], P.b[HD2]);

    // ---- k_down: h_down -> 2 -> 2 ----
    float t2b[ROWS][2], k_down[ROWS][2];
    lin4<4,2,true>(h_down, t2b, P.w[KD1], P.b[KD1]);
    lin4<2,2,true>(t2b, k_down, P.w[KD2], P.b[KD2]);

    // ---- h_act: [h, hd, m_down(6)] -> 4 -> 1 (no relu on last) ----
    float ha_in[ROWS][8], t4c[ROWS][4], h_act[ROWS][1];
#pragma unroll
    for (int k = 0; k < ROWS; ++k) {
        ha_in[k][0] = xin[k][2]; ha_in[k][1] = xin[k][8];
        ha_in[k][2] = m_down[k][0]; ha_in[k][3] = m_down[k][1];
        ha_in[k][4] = m_down[k][2]; ha_in[k][5] = m_down[k][3];
        ha_in[k][6] = m_down[k][4]; ha_in[k][7] = m_down[k][5];
    }
    lin4<8,4,true>(ha_in, t4c, P.w[HA1], P.b[HA1]);
    lin4<4,1,false>(t4c, h_act, P.w[HA2], P.b[HA2]);

    // ---- k_act: [k, kd, h_down(4)] -> 4 -> 1 ----
    float ka_in[ROWS][6], t4d[ROWS][4], k_act[ROWS][1];
#pragma unroll
    for (int k = 0; k < ROWS; ++k) {
        ka_in[k][0] = xin[k][3]; ka_in[k][1] = xin[k][9];
        ka_in[k][2] = h_down[k][0]; ka_in[k][3] = h_down[k][1];
        ka_in[k][4] = h_down[k][2]; ka_in[k][5] = h_down[k][3];
    }
    lin4<6,4,true>(ka_in, t4d, P.w[KA1], P.b[KA1]);
    lin4<4,1,false>(t4d, k_act, P.w[KA2], P.b[KA2]);

    // ---- f_act: [f, fd, k_down(2)] -> 4 -> 1 ----
    float fa_in[ROWS][4], t4e[ROWS][4], f_act[ROWS][1];
#pragma unroll
    for (int k = 0; k < ROWS; ++k) {
        fa_in[k][0] = xin[k][4]; fa_in[k][1] = xin[k][10];
        fa_in[k][2] = k_down[k][0]; fa_in[k][3] = k_down[k][1];
    }
    lin4<4,4,true>(fa_in, t4e, P.w[FA1], P.b[FA1]);
    lin4<4,1,false>(t4e, f_act, P.w[FA2], P.b[FA2]);

    // ---- store: [h_act, f_act, k_act] per row (guarded for tail block) ----
#pragma unroll
    for (int k = 0; k < ROWS; ++k) {
        if (row[k] < B) {
            float* po = out + (long long)row[k] * 3;
            po[0] = h_act[k][0];
            po[1] = f_act[k][0];
            po[2] = k_act[k][0];
        }
    }
}

extern "C" void kernel_launch(void* const* d_in, const int* in_sizes, int n_in,
                              void* d_out, int out_size, void* d_ws, size_t ws_size,
                              hipStream_t stream) {
    const float* x = (const float*)d_in[0];
    float* out = (float*)d_out;
    const int B = in_sizes[0] / 11;

    WPtrs P;
    for (int i = 0; i < 19; ++i) {
        P.w[i] = (const float*)d_in[1 + 2*i];
        P.b[i] = (const float*)d_in[2 + 2*i];
    }

    const long long rows_per_block = (long long)BLOCK * ROWS;
    const int blocks = (int)((B + rows_per_block - 1) / rows_per_block);
    pnet_kernel<<<blocks, BLOCK, 0, stream>>>(x, out, B, P);
}

// Round 2
// 340.170 us; speedup vs baseline: 2.5489x; 2.5489x over previous
//
#include <hip/hip_runtime.h>

#define BLOCK 256
// 2 rows per thread, packed into float2 lanes: v_pk_fma_f32 issues 2 f32 FMAs
// per VALU slot (FP32 peak 157 TF is the PACKED rate; scalar fmac is half).
// Each wave-uniform SGPR weight feeds one packed FMA over 2 independent rows.
// All locals are <=16-element vectors (same promote-alloca size class as the
// 24-VGPR baseline) -- the [4][16] aggregates of R1 were demoted to scratch
// (VGPR=52, 10x regression); this keeps everything register-resident.

typedef float v2f __attribute__((ext_vector_type(2)));

struct WPtrs {
    const float* w[19];
    const float* b[19];
};

enum LId {FU1,FU2,KU1,KU2,HU1,HU2,MD1,MD2,MD3,HD1,HD2,KD1,KD2,HA1,HA2,KA1,KA2,FA1,FA2};

template<int DIN,int DOUT,bool RELU>
__device__ __forceinline__ void lin2(const v2f (&in)[DIN], v2f (&out)[DOUT],
                                     const float* __restrict__ w, const float* __restrict__ b) {
#pragma unroll
    for (int j = 0; j < DOUT; ++j) {
        const float bj = b[j];
        v2f acc = {bj, bj};
#pragma unroll
        for (int i = 0; i < DIN; ++i) {
            const float wv = w[i*DOUT + j];
            const v2f wvv = {wv, wv};
            acc = __builtin_elementwise_fma(in[i], wvv, acc);   // v_pk_fma_f32
        }
        if (RELU) {
            const v2f z = {0.0f, 0.0f};
            acc = __builtin_elementwise_max(acc, z);            // v_pk_max_f32
        }
        out[j] = acc;
    }
}

__global__ __launch_bounds__(BLOCK) void pnet_kernel(
    const float* __restrict__ x, float* __restrict__ out, int B, WPtrs P) {
    const int tid  = threadIdx.x;
    const int rowA = blockIdx.x * (BLOCK * 2) + tid;
    const int rowB = rowA + BLOCK;

    // ---- load 11 features for the two rows into packed lanes ----
    const int rA = rowA < B ? rowA : (B - 1);   // clamp loads; stores guarded below
    const int rB = rowB < B ? rowB : (B - 1);
    const float* pA = x + (long long)rA * 11;
    const float* pB = x + (long long)rB * 11;
    v2f xin[11];
#pragma unroll
    for (int c = 0; c < 11; ++c) { xin[c].x = pA[c]; xin[c].y = pB[c]; }

    // ---- f_up: [f, fd] -> 2 -> 2 ----
    v2f fin[2] = {xin[4], xin[10]};
    v2f tf[2], f_up[2];
    lin2<2,2,true>(fin, tf, P.w[FU1], P.b[FU1]);
    lin2<2,2,true>(tf, f_up, P.w[FU2], P.b[FU2]);

    // ---- k_up: [k, kd, f_up] -> 4 -> 4 ----
    v2f kin[4] = {xin[3], xin[9], f_up[0], f_up[1]};
    v2f tk[4], k_up[4];
    lin2<4,4,true>(kin, tk, P.w[KU1], P.b[KU1]);
    lin2<4,4,true>(tk, k_up, P.w[KU2], P.b[KU2]);

    // ---- h_up: [h, hd, k_up] -> 6 -> 6 ----
    v2f hin[6] = {xin[2], xin[8], k_up[0], k_up[1], k_up[2], k_up[3]};
    v2f th[6], h_up[6];
    lin2<6,6,true>(hin, th, P.w[HU1], P.b[HU1]);
    lin2<6,6,true>(th, h_up, P.w[HU2], P.b[HU2]);

    // ---- m_down: [m_obs(5), h_up(6)] -> 16 -> 16 -> 6 ----
    v2f min_[11] = {xin[0], xin[1], xin[5], xin[6], xin[7],
                    h_up[0], h_up[1], h_up[2], h_up[3], h_up[4], h_up[5]};
    v2f t16a[16], t16b[16], m_down[6];
    lin2<11,16,true>(min_, t16a, P.w[MD1], P.b[MD1]);
    lin2<16,16,true>(t16a, t16b, P.w[MD2], P.b[MD2]);
    lin2<16,6,true>(t16b, m_down, P.w[MD3], P.b[MD3]);

    // ---- h_down: m_down -> 4 -> 4 ----
    v2f t4b[4], h_down[4];
    lin2<6,4,true>(m_down, t4b, P.w[HD1], P.b[HD1]);
    lin2<4,4,true>(t4b, h_down, P.w[HD2], P.b[HD2]);

    // ---- k_down: h_down -> 2 -> 2 ----
    v2f t2b[2], k_down[2];
    lin2<4,2,true>(h_down, t2b, P.w[KD1], P.b[KD1]);
    lin2<2,2,true>(t2b, k_down, P.w[KD2], P.b[KD2]);

    // ---- h_act: [h, hd, m_down(6)] -> 4 -> 1 (no relu on last) ----
    v2f ha_in[8] = {xin[2], xin[8], m_down[0], m_down[1],
                    m_down[2], m_down[3], m_down[4], m_down[5]};
    v2f t4c[4], h_act[1];
    lin2<8,4,true>(ha_in, t4c, P.w[HA1], P.b[HA1]);
    lin2<4,1,false>(t4c, h_act, P.w[HA2], P.b[HA2]);

    // ---- k_act: [k, kd, h_down(4)] -> 4 -> 1 ----
    v2f ka_in[6] = {xin[3], xin[9], h_down[0], h_down[1], h_down[2], h_down[3]};
    v2f t4d[4], k_act[1];
    lin2<6,4,true>(ka_in, t4d, P.w[KA1], P.b[KA1]);
    lin2<4,1,false>(t4d, k_act, P.w[KA2], P.b[KA2]);

    // ---- f_act: [f, fd, k_down(2)] -> 4 -> 1 ----
    v2f fa_in[4] = {xin[4], xin[10], k_down[0], k_down[1]};
    v2f t4e[4], f_act[1];
    lin2<4,4,true>(fa_in, t4e, P.w[FA1], P.b[FA1]);
    lin2<4,1,false>(t4e, f_act, P.w[FA2], P.b[FA2]);

    // ---- store: [h_act, f_act, k_act] per row (guarded for tail) ----
    if (rowA < B) {
        float* po = out + (long long)rowA * 3;
        po[0] = h_act[0].x;
        po[1] = f_act[0].x;
        po[2] = k_act[0].x;
    }
    if (rowB < B) {
        float* po = out + (long long)rowB * 3;
        po[0] = h_act[0].y;
        po[1] = f_act[0].y;
        po[2] = k_act[0].y;
    }
}

extern "C" void kernel_launch(void* const* d_in, const int* in_sizes, int n_in,
                              void* d_out, int out_size, void* d_ws, size_t ws_size,
                              hipStream_t stream) {
    const float* x = (const float*)d_in[0];
    float* out = (float*)d_out;
    const int B = in_sizes[0] / 11;

    WPtrs P;
    for (int i = 0; i < 19; ++i) {
        P.w[i] = (const float*)d_in[1 + 2*i];
        P.b[i] = (const float*)d_in[2 + 2*i];
    }

    const long long rows_per_block = (long long)BLOCK * 2;
    const int blocks = (int)((B + rows_per_block - 1) / rows_per_block);
    pnet_kernel<<<blocks, BLOCK, 0, stream>>>(x, out, B, P);
}

// Round 3
// 245.199 us; speedup vs baseline: 3.5362x; 1.3873x over previous
//
#include <hip/hip_runtime.h>

#define BLOCK 256
// Row-pair packing: 2 rows per thread in float2 lanes -> v_pk_fma_f32.
// R2 failure analysis: the {w,w} splat cost 2 v_mov per weight (VOP3P needs a
// 64-bit source; a 32-bit SGPR can't be used without building a VGPR pair).
// Fix: a prep kernel duplicates every weight/bias into d_ws as {w,w} pairs.
// The pair is then a UNIFORM 64-bit load -> s_load_dwordx2 -> SGPR pair ->
// legal VOP3P source with zero broadcast instructions.
// Per 2 rows: 776 pk_fma + ~89 pair-init + ~82 pk_max  (~500 VALU/row vs ~980
// scalar baseline). Weight s_load stalls amortized over 2 rows.

typedef float v2f __attribute__((ext_vector_type(2)));

struct WPtrs {
    const float* w[19];
    const float* b[19];
};

struct WDup {            // pointers into d_ws: duplicated {v,v} pairs
    const v2f* w[19];
    const v2f* b[19];
};

enum LId {FU1,FU2,KU1,KU2,HU1,HU2,MD1,MD2,MD3,HD1,HD2,KD1,KD2,HA1,HA2,KA1,KA2,FA1,FA2};

__constant__ const int kWN[19] = {4,4,16,16,36,36,176,256,96,24,16,8,4,32,4,24,4,16,4};
__constant__ const int kBN[19] = {2,2,4,4,6,6,16,16,6,4,4,2,2,4,1,4,1,4,1};

// ---- prep: duplicate weights+biases into workspace as {v,v} pairs ----
__global__ void prep_kernel(WPtrs P, float* __restrict__ ws) {
    const int t = threadIdx.x;
    float* dst = ws;
    for (int l = 0; l < 19; ++l) {
        const int wn = kWN[l];
        for (int i = t; i < wn; i += BLOCK) {
            const float v = P.w[l][i];
            dst[2*i] = v; dst[2*i+1] = v;
        }
        dst += 2*wn;
        const int bn = kBN[l];
        for (int i = t; i < bn; i += BLOCK) {
            const float v = P.b[l][i];
            dst[2*i] = v; dst[2*i+1] = v;
        }
        dst += 2*bn;
    }
}

template<int DIN,int DOUT,bool RELU>
__device__ __forceinline__ void lin2(const v2f (&in)[DIN], v2f (&out)[DOUT],
                                     const v2f* __restrict__ wd, const v2f* __restrict__ bd) {
#pragma unroll
    for (int j = 0; j < DOUT; ++j) {
        v2f acc = bd[j];                          // {b,b}: SGPR pair -> v_mov_b64
#pragma unroll
        for (int i = 0; i < DIN; ++i)
            acc = __builtin_elementwise_fma(in[i], wd[i*DOUT + j], acc); // v_pk_fma_f32
        if (RELU) {
            const v2f z = {0.0f, 0.0f};
            acc = __builtin_elementwise_max(acc, z);                     // v_pk_max_f32
        }
        out[j] = acc;
    }
}

__global__ __launch_bounds__(BLOCK) void pnet_kernel(
    const float* __restrict__ x, float* __restrict__ out, int B, WDup P) {
    const int tid  = threadIdx.x;
    const int rowA = blockIdx.x * (BLOCK * 2) + tid;
    const int rowB = rowA + BLOCK;

    const int rA = rowA < B ? rowA : (B - 1);   // clamp loads; stores guarded below
    const int rB = rowB < B ? rowB : (B - 1);
    const float* pA = x + (long long)rA * 11;
    const float* pB = x + (long long)rB * 11;
    v2f xin[11];
#pragma unroll
    for (int c = 0; c < 11; ++c) { xin[c].x = pA[c]; xin[c].y = pB[c]; }

    // ---- f_up: [f, fd] -> 2 -> 2 ----
    v2f fin[2] = {xin[4], xin[10]};
    v2f tf[2], f_up[2];
    lin2<2,2,true>(fin, tf, P.w[FU1], P.b[FU1]);
    lin2<2,2,true>(tf, f_up, P.w[FU2], P.b[FU2]);

    // ---- k_up: [k, kd, f_up] -> 4 -> 4 ----
    v2f kin[4] = {xin[3], xin[9], f_up[0], f_up[1]};
    v2f tk[4], k_up[4];
    lin2<4,4,true>(kin, tk, P.w[KU1], P.b[KU1]);
    lin2<4,4,true>(tk, k_up, P.w[KU2], P.b[KU2]);

    // ---- h_up: [h, hd, k_up] -> 6 -> 6 ----
    v2f hin[6] = {xin[2], xin[8], k_up[0], k_up[1], k_up[2], k_up[3]};
    v2f th[6], h_up[6];
    lin2<6,6,true>(hin, th, P.w[HU1], P.b[HU1]);
    lin2<6,6,true>(th, h_up, P.w[HU2], P.b[HU2]);

    // ---- m_down: [m_obs(5), h_up(6)] -> 16 -> 16 -> 6 ----
    v2f min_[11] = {xin[0], xin[1], xin[5], xin[6], xin[7],
                    h_up[0], h_up[1], h_up[2], h_up[3], h_up[4], h_up[5]};
    v2f t16a[16], t16b[16], m_down[6];
    lin2<11,16,true>(min_, t16a, P.w[MD1], P.b[MD1]);
    lin2<16,16,true>(t16a, t16b, P.w[MD2], P.b[MD2]);
    lin2<16,6,true>(t16b, m_down, P.w[MD3], P.b[MD3]);

    // ---- h_down: m_down -> 4 -> 4 ----
    v2f t4b[4], h_down[4];
    lin2<6,4,true>(m_down, t4b, P.w[HD1], P.b[HD1]);
    lin2<4,4,true>(t4b, h_down, P.w[HD2], P.b[HD2]);

    // ---- k_down: h_down -> 2 -> 2 ----
    v2f t2b[2], k_down[2];
    lin2<4,2,true>(h_down, t2b, P.w[KD1], P.b[KD1]);
    lin2<2,2,true>(t2b, k_down, P.w[KD2], P.b[KD2]);

    // ---- h_act: [h, hd, m_down(6)] -> 4 -> 1 (no relu on last) ----
    v2f ha_in[8] = {xin[2], xin[8], m_down[0], m_down[1],
                    m_down[2], m_down[3], m_down[4], m_down[5]};
    v2f t4c[4], h_act[1];
    lin2<8,4,true>(ha_in, t4c, P.w[HA1], P.b[HA1]);
    lin2<4,1,false>(t4c, h_act, P.w[HA2], P.b[HA2]);   // acc pair = {rowA, rowB}

    // ---- k_act: [k, kd, h_down(4)] -> 4 -> 1 ----
    v2f ka_in[6] = {xin[3], xin[9], h_down[0], h_down[1], h_down[2], h_down[3]};
    v2f t4d[4], k_act[1];
    lin2<6,4,true>(ka_in, t4d, P.w[KA1], P.b[KA1]);
    lin2<4,1,false>(t4d, k_act, P.w[KA2], P.b[KA2]);

    // ---- f_act: [f, fd, k_down(2)] -> 4 -> 1 ----
    v2f fa_in[4] = {xin[4], xin[10], k_down[0], k_down[1]};
    v2f t4e[4], f_act[1];
    lin2<4,4,true>(fa_in, t4e, P.w[FA1], P.b[FA1]);
    lin2<4,1,false>(t4e, f_act, P.w[FA2], P.b[FA2]);

    // ---- store: [h_act, f_act, k_act] per row (guarded for tail) ----
    if (rowA < B) {
        float* po = out + (long long)rowA * 3;
        po[0] = h_act[0].x;
        po[1] = f_act[0].x;
        po[2] = k_act[0].x;
    }
    if (rowB < B) {
        float* po = out + (long long)rowB * 3;
        po[0] = h_act[0].y;
        po[1] = f_act[0].y;
        po[2] = k_act[0].y;
    }
}

extern "C" void kernel_launch(void* const* d_in, const int* in_sizes, int n_in,
                              void* d_out, int out_size, void* d_ws, size_t ws_size,
                              hipStream_t stream) {
    static const int wn[19] = {4,4,16,16,36,36,176,256,96,24,16,8,4,32,4,24,4,16,4};
    static const int bn[19] = {2,2,4,4,6,6,16,16,6,4,4,2,2,4,1,4,1,4,1};

    const float* x = (const float*)d_in[0];
    float* out = (float*)d_out;
    const int B = in_sizes[0] / 11;

    WPtrs P;
    for (int i = 0; i < 19; ++i) {
        P.w[i] = (const float*)d_in[1 + 2*i];
        P.b[i] = (const float*)d_in[2 + 2*i];
    }

    float* ws = (float*)d_ws;
    WDup D;
    int off = 0;
    for (int l = 0; l < 19; ++l) {
        D.w[l] = (const v2f*)(ws + off); off += 2 * wn[l];
        D.b[l] = (const v2f*)(ws + off); off += 2 * bn[l];
    }

    prep_kernel<<<1, BLOCK, 0, stream>>>(P, ws);   // ~7 KB, ordered before main

    const long long rows_per_block = (long long)BLOCK * 2;
    const int blocks = (int)((B + rows_per_block - 1) / rows_per_block);
    pnet_kernel<<<blocks, BLOCK, 0, stream>>>(x, out, B, D);
}